// Round 1
// baseline (274.784 us; speedup 1.0000x reference)
//
#include <hip/hip_runtime.h>

// Problem constants (fixed by reference)
#define NV 4000
#define NH 512
#define NM 50
#define CAP 96
#define NHOPS 6

// ---------------------------------------------------------------------------
// K0: block 0..127 compute w2q[k] = sum_c W2[k,c]*q[c]; blocks 128..143 zero
//     the accumulator region and init out = bo2.
__global__ void k_init(const float* __restrict__ query, const float* __restrict__ W2,
                       const float* __restrict__ bo2, float* __restrict__ w2q,
                       float* __restrict__ zreg, float* __restrict__ out) {
    int b = blockIdx.x;
    if (b < 128) {
        __shared__ float qs[NH];
        qs[threadIdx.x] = query[threadIdx.x];
        qs[threadIdx.x + 256] = query[threadIdx.x + 256];
        __syncthreads();
        int wid = threadIdx.x >> 6, lane = threadIdx.x & 63;
        int k = b * 4 + wid;
        const float* wr = W2 + (size_t)k * NH;
        float p = 0.f;
        for (int j = lane; j < NH; j += 64) p = fmaf(wr[j], qs[j], p);
        for (int o = 32; o > 0; o >>= 1) p += __shfl_down(p, o);
        if (lane == 0) w2q[k] = p;
    } else {
        int t = (b - 128) * 256 + threadIdx.x;           // 0..4095
        for (int i = t; i < 53312; i += 4096) zreg[i] = 0.f;
        for (int i = t; i < NV; i += 4096) out[i] = bo2[i];
    }
}

// ---------------------------------------------------------------------------
// K1: build per-row sparse structure of adj (block per row, coalesced scan)
__global__ void k_csr(const float* __restrict__ adj, int* __restrict__ rcnt,
                      int* __restrict__ cols, float* __restrict__ vals) {
    int r = blockIdx.x;
    __shared__ int cnt;
    if (threadIdx.x == 0) cnt = 0;
    __syncthreads();
    const float* row = adj + (size_t)r * NV;
    for (int c = threadIdx.x; c < NV; c += 256) {
        float a = row[c];
        if (a != 0.f) {
            int i = atomicAdd(&cnt, 1);
            if (i < CAP) { cols[r * CAP + i] = c; vals[r * CAP + i] = a; }
        }
    }
    __syncthreads();
    if (threadIdx.x == 0) rcnt[r] = cnt < CAP ? cnt : CAP;
}

// ---------------------------------------------------------------------------
// K2: h = relu(spmm(adj, W1) + b1)      (block per row, 2 cols/thread)
__global__ void k_spmm_h(const int* __restrict__ rcnt, const int* __restrict__ cols,
                         const float* __restrict__ vals, const float* __restrict__ W1,
                         const float* __restrict__ b1, float* __restrict__ h) {
    int r = blockIdx.x;
    __shared__ int cs[CAP];
    __shared__ float vs[CAP];
    int cnt = rcnt[r];
    if (threadIdx.x < cnt) {
        cs[threadIdx.x] = cols[r * CAP + threadIdx.x];
        vs[threadIdx.x] = vals[r * CAP + threadIdx.x];
    }
    __syncthreads();
    int c0 = threadIdx.x, c1 = threadIdx.x + 256;
    float a0 = b1[c0], a1 = b1[c1];
    for (int j = 0; j < cnt; ++j) {
        const float* wr = W1 + (size_t)cs[j] * NH;
        float v = vs[j];
        a0 = fmaf(v, wr[c0], a0);
        a1 = fmaf(v, wr[c1], a1);
    }
    h[(size_t)r * NH + c0] = fmaxf(a0, 0.f);
    h[(size_t)r * NH + c1] = fmaxf(a1, 0.f);
}

// ---------------------------------------------------------------------------
// K3: g = spmm(adj, h); fused logits_e[r] = dot(g[r,:], w2q)
__global__ void k_spmm_g(const int* __restrict__ rcnt, const int* __restrict__ cols,
                         const float* __restrict__ vals, const float* __restrict__ h,
                         const float* __restrict__ w2q, float* __restrict__ g,
                         float* __restrict__ logits) {
    int r = blockIdx.x;
    __shared__ int cs[CAP];
    __shared__ float vs[CAP];
    __shared__ float red[4];
    int cnt = rcnt[r];
    if (threadIdx.x < cnt) {
        cs[threadIdx.x] = cols[r * CAP + threadIdx.x];
        vs[threadIdx.x] = vals[r * CAP + threadIdx.x];
    }
    __syncthreads();
    int c0 = threadIdx.x, c1 = threadIdx.x + 256;
    float a0 = 0.f, a1 = 0.f;
    for (int j = 0; j < cnt; ++j) {
        const float* hr = h + (size_t)cs[j] * NH;
        float v = vs[j];
        a0 = fmaf(v, hr[c0], a0);
        a1 = fmaf(v, hr[c1], a1);
    }
    g[(size_t)r * NH + c0] = a0;
    g[(size_t)r * NH + c1] = a1;
    float p = a0 * w2q[c0] + a1 * w2q[c1];
    for (int o = 32; o > 0; o >>= 1) p += __shfl_down(p, o);
    if ((threadIdx.x & 63) == 0) red[threadIdx.x >> 6] = p;
    __syncthreads();
    if (threadIdx.x == 0) logits[r] = red[0] + red[1] + red[2] + red[3];
}

// ---------------------------------------------------------------------------
// K4: P += mvmh_chunk @ g_chunk  (125 blocks x 32 rows), also s = rowsum(mvmh)
__global__ void k_P(const float* __restrict__ mvmh, const float* __restrict__ g,
                    float* __restrict__ P, float* __restrict__ s) {
    int v0 = blockIdx.x * 32;
    int c = threadIdx.x;  // 0..511
    __shared__ float mv[NM][32];
    for (int i = threadIdx.x; i < NM * 32; i += 512) {
        int m = i >> 5, j = i & 31;
        mv[m][j] = mvmh[(size_t)m * NV + v0 + j];
    }
    __syncthreads();
    float acc[NM];
#pragma unroll
    for (int m = 0; m < NM; ++m) acc[m] = 0.f;
    for (int j = 0; j < 32; ++j) {
        float gv = g[(size_t)(v0 + j) * NH + c];
#pragma unroll
        for (int m = 0; m < NM; ++m) acc[m] = fmaf(mv[m][j], gv, acc[m]);
    }
#pragma unroll
    for (int m = 0; m < NM; ++m) atomicAdd(&P[m * NH + c], acc[m]);
    if (threadIdx.x < NM) {
        float ss = 0.f;
        for (int j = 0; j < 32; ++j) ss += mv[threadIdx.x][j];
        atomicAdd(&s[threadIdx.x], ss);
    }
}

// ---------------------------------------------------------------------------
// K5: aw_e = softmax(logits_e) over 4000 (single block)
__global__ void k_softmax(const float* __restrict__ logits, float* __restrict__ aw) {
    __shared__ float ls[NV];
    __shared__ float red[256];
    int t = threadIdx.x;
    float mx = -1e30f;
    for (int i = t; i < NV; i += 256) { float x = logits[i]; ls[i] = x; mx = fmaxf(mx, x); }
    red[t] = mx; __syncthreads();
    for (int o = 128; o > 0; o >>= 1) { if (t < o) red[t] = fmaxf(red[t], red[t + o]); __syncthreads(); }
    mx = red[0]; __syncthreads();
    float sm = 0.f;
    for (int i = t; i < NV; i += 256) sm += expf(ls[i] - mx);
    red[t] = sm; __syncthreads();
    for (int o = 128; o > 0; o >>= 1) { if (t < o) red[t] += red[t + o]; __syncthreads(); }
    sm = red[0];
    float inv = 1.f / sm;
    for (int i = t; i < NV; i += 256) aw[i] = expf(ls[i] - mx) * inv;
}

// ---------------------------------------------------------------------------
// K6: ctxg += aw_e_chunk @ g_chunk
__global__ void k_ctxg(const float* __restrict__ aw, const float* __restrict__ g,
                       float* __restrict__ ctxg) {
    int v0 = blockIdx.x * 32;
    int c = threadIdx.x;  // 0..511
    __shared__ float aws[32];
    if (c < 32) aws[c] = aw[v0 + c];
    __syncthreads();
    float acc = 0.f;
    for (int j = 0; j < 32; ++j) acc = fmaf(aws[j], g[(size_t)(v0 + j) * NH + c], acc);
    atomicAdd(&ctxg[c], acc);
}

// ---------------------------------------------------------------------------
// K7: rows {P[0..49], ctxg} times W2 (split-K x8) -> {R rows, ctxE}
__global__ void k_rowsW2(const float* __restrict__ P, const float* __restrict__ ctxg,
                         const float* __restrict__ W2, float* __restrict__ R,
                         float* __restrict__ ctxE) {
    int blk = blockIdx.x;
    int m = blk >> 3, ks = blk & 7;
    int c = threadIdx.x;  // 0..511
    __shared__ float xr[64];
    const float* src = (m < NM) ? P + (size_t)m * NH : ctxg;
    if (c < 64) xr[c] = src[ks * 64 + c];
    __syncthreads();
    float acc = 0.f;
    const float* wp = W2 + (size_t)(ks * 64) * NH + c;
#pragma unroll 8
    for (int j = 0; j < 64; ++j) acc = fmaf(xr[j], wp[(size_t)j * NH], acc);
    if (m < NM) atomicAdd(&R[m * NH + c], acc);
    else atomicAdd(&ctxE[c], acc);
}

// ---------------------------------------------------------------------------
// K8: R[m,:] += s[m]*b2 ; ctxE += b2
__global__ void k_finalize(const float* __restrict__ b2, const float* __restrict__ s,
                           float* __restrict__ R, float* __restrict__ ctxE) {
    int b = blockIdx.x, c = threadIdx.x;
    if (b < NM) R[b * NH + c] += s[b] * b2[c];
    else ctxE[c] += b2[c];
}

// ---------------------------------------------------------------------------
// K9: G[b,m] = dot(R[b,:], keys[m,:]);  KQ[m] = dot(query, keys[m,:])  (b==50)
__global__ void k_KQG(const float* __restrict__ R, const float* __restrict__ query,
                      const float* __restrict__ keys, float* __restrict__ G,
                      float* __restrict__ KQ) {
    int b = blockIdx.x;
    __shared__ float xs[NH];
    const float* src = (b < NM) ? R + (size_t)b * NH : query;
    xs[threadIdx.x] = src[threadIdx.x];
    xs[threadIdx.x + 256] = src[threadIdx.x + 256];
    __syncthreads();
    int wid = threadIdx.x >> 6, lane = threadIdx.x & 63;
    for (int m = wid; m < NM; m += 4) {
        const float* kr = keys + (size_t)m * NH;
        float p = 0.f;
        for (int j = lane; j < NH; j += 64) p = fmaf(kr[j], xs[j], p);
        for (int o = 32; o > 0; o >>= 1) p += __shfl_down(p, o);
        if (lane == 0) {
            if (b < NM) G[b * NM + m] = p;
            else KQ[m] = p;
        }
    }
}

// ---------------------------------------------------------------------------
// K10: 6 sequential hops entirely in 50-dim space (single wave)
__global__ void k_hops(const float* __restrict__ KQ, const float* __restrict__ G,
                       float* __restrict__ A) {
    __shared__ float Gs[NM * NM];
    __shared__ float aws[64];
    int l = threadIdx.x;  // 0..63
    for (int i = l; i < NM * NM; i += 64) Gs[i] = G[i];
    __syncthreads();
    float L = (l < NM) ? KQ[l] : -1e30f;
    float Aacc = 0.f;
    for (int t = 0; t < NHOPS; ++t) {
        float mx = L;
        for (int o = 32; o > 0; o >>= 1) mx = fmaxf(mx, __shfl_xor(mx, o));
        float e = (l < NM) ? expf(L - mx) : 0.f;
        float sm = e;
        for (int o = 32; o > 0; o >>= 1) sm += __shfl_xor(sm, o);
        float aw = e / sm;
        Aacc += aw;
        aws[l] = aw;
        __syncthreads();
        if (l < NM) {
            float d = 0.f;
            for (int mp = 0; mp < NM; ++mp) d = fmaf(aws[mp], Gs[mp * NM + l], d);
            L += d;
        }
        __syncthreads();
    }
    if (l < NM) A[l] = Aacc;
}

// ---------------------------------------------------------------------------
// K11: context_o = query + A @ R ; feat = relu([query, context_o, ctxE])
__global__ void k_ctxo_feat(const float* __restrict__ query, const float* __restrict__ A,
                            const float* __restrict__ R, const float* __restrict__ ctxE,
                            float* __restrict__ feat) {
    __shared__ float As[NM];
    int c = threadIdx.x;  // 0..511
    if (c < NM) As[c] = A[c];
    __syncthreads();
    float q = query[c];
    float acc = q;
#pragma unroll 5
    for (int m = 0; m < NM; ++m) acc = fmaf(As[m], R[m * NH + c], acc);
    feat[c] = fmaxf(q, 0.f);
    feat[NH + c] = fmaxf(acc, 0.f);
    feat[2 * NH + c] = fmaxf(ctxE[c], 0.f);
}

// ---------------------------------------------------------------------------
// K12: hid += feat @ Wo1 chunk (split-K x12, j-tiles x4)
__global__ void k_gemv1(const float* __restrict__ feat, const float* __restrict__ Wo1,
                        float* __restrict__ hid) {
    int blk = blockIdx.x;
    int jt = blk & 3, ks = blk >> 2;  // ks 0..11
    int j = jt * 256 + threadIdx.x;
    int k0 = ks * 128;
    __shared__ float fs[128];
    if (threadIdx.x < 128) fs[threadIdx.x] = feat[k0 + threadIdx.x];
    __syncthreads();
    float acc = 0.f;
    const float* wp = Wo1 + (size_t)k0 * 1024 + j;
#pragma unroll 8
    for (int i = 0; i < 128; ++i) acc = fmaf(fs[i], wp[(size_t)i * 1024], acc);
    atomicAdd(&hid[j], acc);
}

// ---------------------------------------------------------------------------
// K13: out += relu(hid + bo1) @ Wo2 chunk (split-K x8, v-tiles x16)
__global__ void k_gemv2(const float* __restrict__ hid, const float* __restrict__ bo1,
                        const float* __restrict__ Wo2, float* __restrict__ out) {
    int blk = blockIdx.x;
    int vt = blk & 15, ks = blk >> 4;  // ks 0..7
    int v = vt * 256 + threadIdx.x;
    int k0 = ks * 128;
    __shared__ float rh[128];
    if (threadIdx.x < 128) {
        float x = hid[k0 + threadIdx.x] + bo1[k0 + threadIdx.x];
        rh[threadIdx.x] = fmaxf(x, 0.f);
    }
    __syncthreads();
    if (v < NV) {
        float acc = 0.f;
        const float* wp = Wo2 + (size_t)k0 * NV + v;
#pragma unroll 8
        for (int i = 0; i < 128; ++i) acc = fmaf(rh[i], wp[(size_t)i * NV], acc);
        atomicAdd(&out[v], acc);
    }
}

// ---------------------------------------------------------------------------
extern "C" void kernel_launch(void* const* d_in, const int* in_sizes, int n_in,
                              void* d_out, int out_size, void* d_ws, size_t ws_size,
                              hipStream_t stream) {
    const float* query = (const float*)d_in[0];
    const float* keys  = (const float*)d_in[1];
    const float* mvmh  = (const float*)d_in[2];
    const float* adj   = (const float*)d_in[3];
    const float* W1    = (const float*)d_in[4];
    const float* b1    = (const float*)d_in[5];
    const float* W2    = (const float*)d_in[6];
    const float* b2    = (const float*)d_in[7];
    const float* Wo1   = (const float*)d_in[8];
    const float* bo1   = (const float*)d_in[9];
    const float* Wo2   = (const float*)d_in[10];
    const float* bo2   = (const float*)d_in[11];
    float* out = (float*)d_out;

    char* w = (char*)d_ws;
    int* rcnt = (int*)w;        w += 4096 * 4;
    int* cols = (int*)w;        w += NV * CAP * 4;
    float* vals = (float*)w;    w += NV * CAP * 4;
    float* h = (float*)w;       w += (size_t)NV * NH * 4;
    float* g = (float*)w;       w += (size_t)NV * NH * 4;
    // zero region (53312 floats, contiguous):
    float* zreg = (float*)w;
    float* P = (float*)w;       w += NM * NH * 4;       // 25600
    float* R = (float*)w;       w += NM * NH * 4;       // 25600
    float* s = (float*)w;       w += 64 * 4;            // 64
    float* ctxg = (float*)w;    w += NH * 4;            // 512
    float* ctxE = (float*)w;    w += NH * 4;            // 512
    float* hid = (float*)w;     w += 1024 * 4;          // 1024
    // non-zeroed scratch:
    float* w2q = (float*)w;     w += NH * 4;
    float* logits = (float*)w;  w += 4096 * 4;
    float* aw_e = (float*)w;    w += 4096 * 4;
    float* KQ = (float*)w;      w += 64 * 4;
    float* G = (float*)w;       w += NM * NM * 4;
    float* A = (float*)w;       w += 64 * 4;
    float* feat = (float*)w;    w += 1536 * 4;

    k_init<<<144, 256, 0, stream>>>(query, W2, bo2, w2q, zreg, out);
    k_csr<<<NV, 256, 0, stream>>>(adj, rcnt, cols, vals);
    k_spmm_h<<<NV, 256, 0, stream>>>(rcnt, cols, vals, W1, b1, h);
    k_spmm_g<<<NV, 256, 0, stream>>>(rcnt, cols, vals, h, w2q, g, logits);
    k_P<<<125, 512, 0, stream>>>(mvmh, g, P, s);
    k_softmax<<<1, 256, 0, stream>>>(logits, aw_e);
    k_ctxg<<<125, 512, 0, stream>>>(aw_e, g, ctxg);
    k_rowsW2<<<51 * 8, 512, 0, stream>>>(P, ctxg, W2, R, ctxE);
    k_finalize<<<51, 512, 0, stream>>>(b2, s, R, ctxE);
    k_KQG<<<51, 256, 0, stream>>>(R, query, keys, G, KQ);
    k_hops<<<1, 64, 0, stream>>>(KQ, G, A);
    k_ctxo_feat<<<1, 512, 0, stream>>>(query, A, R, ctxE, feat);
    k_gemv1<<<48, 256, 0, stream>>>(feat, Wo1, hid);
    k_gemv2<<<128, 256, 0, stream>>>(hid, bo1, Wo2, out);
}

// Round 2
// 262.148 us; speedup vs baseline: 1.0482x; 1.0482x over previous
//
#include <hip/hip_runtime.h>

// Problem constants (fixed by reference)
#define NV 4000
#define NH 512
#define NM 50
#define CAP 96
#define NHOPS 6
#define VS 25          // v-splits in k5
#define VCH 160        // NV / VS
#define CB 16          // c-chunk blocks in k5 (32 cols per block, 8 per wave)

// ---------------------------------------------------------------------------
// K1: b<4000: CSR build (float4 scan). b in [4000,4128): w2q = W2 @ q.
//     b in [4128,4144): out = bo2, zero s/hid region.
__global__ void k1_init_csr(const float* __restrict__ adj, const float* __restrict__ query,
                            const float* __restrict__ W2, const float* __restrict__ bo2,
                            int* __restrict__ rcnt, int* __restrict__ cols, float* __restrict__ vals,
                            float* __restrict__ w2q, float* __restrict__ zreg, float* __restrict__ out) {
    int b = blockIdx.x;
    if (b < NV) {
        __shared__ int cnt;
        if (threadIdx.x == 0) cnt = 0;
        __syncthreads();
        const float4* row4 = (const float4*)(adj + (size_t)b * NV);
        for (int i = threadIdx.x; i < NV / 4; i += 256) {
            float4 a = row4[i];
            if (a.x != 0.f) { int k = atomicAdd(&cnt, 1); if (k < CAP) { cols[b*CAP+k] = 4*i;   vals[b*CAP+k] = a.x; } }
            if (a.y != 0.f) { int k = atomicAdd(&cnt, 1); if (k < CAP) { cols[b*CAP+k] = 4*i+1; vals[b*CAP+k] = a.y; } }
            if (a.z != 0.f) { int k = atomicAdd(&cnt, 1); if (k < CAP) { cols[b*CAP+k] = 4*i+2; vals[b*CAP+k] = a.z; } }
            if (a.w != 0.f) { int k = atomicAdd(&cnt, 1); if (k < CAP) { cols[b*CAP+k] = 4*i+3; vals[b*CAP+k] = a.w; } }
        }
        __syncthreads();
        if (threadIdx.x == 0) rcnt[b] = cnt < CAP ? cnt : CAP;
    } else if (b < NV + 128) {
        __shared__ float qs[NH];
        qs[threadIdx.x] = query[threadIdx.x];
        qs[threadIdx.x + 256] = query[threadIdx.x + 256];
        __syncthreads();
        int wid = threadIdx.x >> 6, lane = threadIdx.x & 63;
        int k = (b - NV) * 4 + wid;
        const float* wr = W2 + (size_t)k * NH;
        float p = 0.f;
        for (int j = lane; j < NH; j += 64) p = fmaf(wr[j], qs[j], p);
        for (int o = 32; o > 0; o >>= 1) p += __shfl_down(p, o);
        if (lane == 0) w2q[k] = p;
    } else {
        int t = (b - NV - 128) * 256 + threadIdx.x;   // 0..4095
        if (t < NV) out[t] = bo2[t];
        if (t < 1088) zreg[t] = 0.f;                  // s[64] + hid[1024]
    }
}

// ---------------------------------------------------------------------------
// K2: h = relu(spmm(adj, W1) + b1)   (block per row, float2 per thread)
__global__ void k2_spmm_h(const int* __restrict__ rcnt, const int* __restrict__ cols,
                          const float* __restrict__ vals, const float* __restrict__ W1,
                          const float* __restrict__ b1, float* __restrict__ h) {
    int r = blockIdx.x;
    __shared__ float2 cv[CAP];
    int cnt = rcnt[r];
    if (threadIdx.x < cnt) {
        cv[threadIdx.x].x = __int_as_float(cols[r * CAP + threadIdx.x] * NH);
        cv[threadIdx.x].y = vals[r * CAP + threadIdx.x];
    }
    __syncthreads();
    int c = threadIdx.x * 2;
    float2 acc = *(const float2*)(b1 + c);
    for (int j = 0; j < cnt; ++j) {
        float2 p = cv[j];
        const float2 w = *(const float2*)(W1 + (size_t)__float_as_int(p.x) + c);
        acc.x = fmaf(p.y, w.x, acc.x);
        acc.y = fmaf(p.y, w.y, acc.y);
    }
    acc.x = fmaxf(acc.x, 0.f);
    acc.y = fmaxf(acc.y, 0.f);
    *(float2*)(h + (size_t)r * NH + c) = acc;
}

// ---------------------------------------------------------------------------
// K3: g = spmm(adj, h); fused logits[r] = dot(g[r,:], w2q)
__global__ void k3_spmm_g(const int* __restrict__ rcnt, const int* __restrict__ cols,
                          const float* __restrict__ vals, const float* __restrict__ h,
                          const float* __restrict__ w2q, float* __restrict__ g,
                          float* __restrict__ logits) {
    int r = blockIdx.x;
    __shared__ float2 cv[CAP];
    __shared__ float red[4];
    int cnt = rcnt[r];
    if (threadIdx.x < cnt) {
        cv[threadIdx.x].x = __int_as_float(cols[r * CAP + threadIdx.x] * NH);
        cv[threadIdx.x].y = vals[r * CAP + threadIdx.x];
    }
    __syncthreads();
    int c = threadIdx.x * 2;
    float2 acc = {0.f, 0.f};
    for (int j = 0; j < cnt; ++j) {
        float2 p = cv[j];
        const float2 w = *(const float2*)(h + (size_t)__float_as_int(p.x) + c);
        acc.x = fmaf(p.y, w.x, acc.x);
        acc.y = fmaf(p.y, w.y, acc.y);
    }
    *(float2*)(g + (size_t)r * NH + c) = acc;
    float2 wq = *(const float2*)(w2q + c);
    float pp = acc.x * wq.x + acc.y * wq.y;
    for (int o = 32; o > 0; o >>= 1) pp += __shfl_down(pp, o);
    if ((threadIdx.x & 63) == 0) red[threadIdx.x >> 6] = pp;
    __syncthreads();
    if (threadIdx.x == 0) logits[r] = red[0] + red[1] + red[2] + red[3];
}

// ---------------------------------------------------------------------------
// K5: Ppart[vs] = mvmh_chunk @ g_chunk, Epart[vs] = aw_e_chunk @ g_chunk,
//     s = rowsum(mvmh). lane = m; g fetched as wave-uniform broadcast float4;
//     mvmh chunk staged in LDS (stride 161 -> 2-way bank alias, free).
//     Softmax scalars (mx, inv) computed redundantly per block.
__global__ void k5_PE(const float* __restrict__ mvmh, const float* __restrict__ g,
                      const float* __restrict__ logits, float* __restrict__ Ppart,
                      float* __restrict__ Epart, float* __restrict__ s) {
    __shared__ float mvs[NM * (VCH + 1)];
    __shared__ float es[VCH];
    __shared__ float red[4];
    int cb = blockIdx.x & (CB - 1);
    int vs = blockIdx.x / CB;
    int v0 = vs * VCH;
    int tid = threadIdx.x;

    // stage mv chunk
    for (int i = tid; i < NM * VCH; i += 256) {
        int m = i / VCH, vv = i - m * VCH;
        mvs[m * (VCH + 1) + vv] = mvmh[(size_t)m * NV + v0 + vv];
    }
    // block-redundant softmax scalars over logits[0..3999]
    float lmx = -1e30f;
    for (int i = tid; i < NV; i += 256) lmx = fmaxf(lmx, logits[i]);
    for (int o = 32; o > 0; o >>= 1) lmx = fmaxf(lmx, __shfl_xor(lmx, o));
    if ((tid & 63) == 0) red[tid >> 6] = lmx;
    __syncthreads();
    float mx = fmaxf(fmaxf(red[0], red[1]), fmaxf(red[2], red[3]));
    __syncthreads();
    float lsum = 0.f;
    for (int i = tid; i < NV; i += 256) lsum += __expf(logits[i] - mx);
    for (int o = 32; o > 0; o >>= 1) lsum += __shfl_xor(lsum, o);
    if ((tid & 63) == 0) red[tid >> 6] = lsum;
    __syncthreads();
    float inv = 1.f / (red[0] + red[1] + red[2] + red[3]);
    // stage e-weights for this v-chunk
    for (int i = tid; i < VCH; i += 256) es[i] = __expf(logits[v0 + i] - mx) * inv;
    __syncthreads();

    int w = tid >> 6, l = tid & 63;
    int C = cb * 32 + w * 8;
    int lc = (l < NM) ? l : 0;
    const float* mrow = mvs + lc * (VCH + 1);
    float acc[8], ace[8];
    float accs = 0.f;
#pragma unroll
    for (int i = 0; i < 8; ++i) { acc[i] = 0.f; ace[i] = 0.f; }
    for (int vv = 0; vv < VCH; ++vv) {
        int v = v0 + vv;
        float t = mrow[vv];
        float ve = es[vv];
        float4 ga = *(const float4*)(g + (size_t)v * NH + C);
        float4 gb = *(const float4*)(g + (size_t)v * NH + C + 4);
        acc[0] = fmaf(t, ga.x, acc[0]); ace[0] = fmaf(ve, ga.x, ace[0]);
        acc[1] = fmaf(t, ga.y, acc[1]); ace[1] = fmaf(ve, ga.y, ace[1]);
        acc[2] = fmaf(t, ga.z, acc[2]); ace[2] = fmaf(ve, ga.z, ace[2]);
        acc[3] = fmaf(t, ga.w, acc[3]); ace[3] = fmaf(ve, ga.w, ace[3]);
        acc[4] = fmaf(t, gb.x, acc[4]); ace[4] = fmaf(ve, gb.x, ace[4]);
        acc[5] = fmaf(t, gb.y, acc[5]); ace[5] = fmaf(ve, gb.y, ace[5]);
        acc[6] = fmaf(t, gb.z, acc[6]); ace[6] = fmaf(ve, gb.z, ace[6]);
        acc[7] = fmaf(t, gb.w, acc[7]); ace[7] = fmaf(ve, gb.w, ace[7]);
        accs += t;
    }
    if (l < NM) {
        float* dst = Ppart + ((size_t)vs * NM + l) * NH + C;
        float4 o0 = {acc[0], acc[1], acc[2], acc[3]};
        float4 o1 = {acc[4], acc[5], acc[6], acc[7]};
        *(float4*)dst = o0;
        *(float4*)(dst + 4) = o1;
    }
    if (l == 0) {
        float* dst = Epart + (size_t)vs * NH + C;
        float4 e0 = {ace[0], ace[1], ace[2], ace[3]};
        float4 e1 = {ace[4], ace[5], ace[6], ace[7]};
        *(float4*)dst = e0;
        *(float4*)(dst + 4) = e1;
    }
    if (cb == 0 && w == 0 && l < NM) atomicAdd(&s[l], accs);
}

// ---------------------------------------------------------------------------
// K6: reduce partials, then full-K row x W2: R[m] = P[m]@W2 + s[m]*b2 (m<50),
//     ctxE = E@W2 + b2 (m==50). No atomics, ds_read_b128 on xs.
__global__ void k6_rowsW2(const float* __restrict__ Ppart, const float* __restrict__ Epart,
                          const float* __restrict__ W2, const float* __restrict__ b2,
                          const float* __restrict__ s, float* __restrict__ R,
                          float* __restrict__ ctxE) {
    int m = blockIdx.x;
    __shared__ float xs[NH];
    int tid = threadIdx.x;   // 256
    if (m < NM) {
        for (int k = tid; k < NH; k += 256) {
            float v = 0.f;
            const float* p = Ppart + (size_t)m * NH + k;
            for (int q = 0; q < VS; ++q) v += p[(size_t)q * NM * NH];
            xs[k] = v;
        }
    } else {
        for (int k = tid; k < NH; k += 256) {
            float v = 0.f;
            for (int q = 0; q < VS; ++q) v += Epart[(size_t)q * NH + k];
            xs[k] = v;
        }
    }
    __syncthreads();
    int c = tid * 2;
    float2 acc = {0.f, 0.f};
    const float4* xs4 = (const float4*)xs;
    for (int kk = 0; kk < NH / 4; ++kk) {
        float4 x = xs4[kk];
        int k = kk * 4;
        float2 w0 = *(const float2*)(W2 + (size_t)k * NH + c);
        float2 w1 = *(const float2*)(W2 + (size_t)(k + 1) * NH + c);
        float2 w2v = *(const float2*)(W2 + (size_t)(k + 2) * NH + c);
        float2 w3 = *(const float2*)(W2 + (size_t)(k + 3) * NH + c);
        acc.x = fmaf(x.x, w0.x, acc.x);  acc.y = fmaf(x.x, w0.y, acc.y);
        acc.x = fmaf(x.y, w1.x, acc.x);  acc.y = fmaf(x.y, w1.y, acc.y);
        acc.x = fmaf(x.z, w2v.x, acc.x); acc.y = fmaf(x.z, w2v.y, acc.y);
        acc.x = fmaf(x.w, w3.x, acc.x);  acc.y = fmaf(x.w, w3.y, acc.y);
    }
    float2 bb = *(const float2*)(b2 + c);
    if (m < NM) {
        float sm = s[m];
        acc.x += sm * bb.x;
        acc.y += sm * bb.y;
        *(float2*)(R + (size_t)m * NH + c) = acc;
    } else {
        acc.x += bb.x;
        acc.y += bb.y;
        *(float2*)(ctxE + c) = acc;
    }
}

// ---------------------------------------------------------------------------
// K7: G[b,m] = dot(R[b,:], keys[m,:]);  KQ[m] = dot(query, keys[m,:]) (b==50)
__global__ void k7_KQG(const float* __restrict__ R, const float* __restrict__ query,
                       const float* __restrict__ keys, float* __restrict__ G,
                       float* __restrict__ KQ) {
    int b = blockIdx.x;
    __shared__ float xs[NH];
    const float* src = (b < NM) ? R + (size_t)b * NH : query;
    xs[threadIdx.x] = src[threadIdx.x];
    xs[threadIdx.x + 256] = src[threadIdx.x + 256];
    __syncthreads();
    int wid = threadIdx.x >> 6, lane = threadIdx.x & 63;
    for (int m = wid; m < NM; m += 4) {
        const float* kr = keys + (size_t)m * NH;
        float p = 0.f;
        for (int j = lane; j < NH; j += 64) p = fmaf(kr[j], xs[j], p);
        for (int o = 32; o > 0; o >>= 1) p += __shfl_down(p, o);
        if (lane == 0) {
            if (b < NM) G[b * NM + m] = p;
            else KQ[m] = p;
        }
    }
}

// ---------------------------------------------------------------------------
// K9: blocks needing feat[512..1024) run the 6-hop 50-dim recurrence
//     redundantly (wave 0), then all blocks compute their fs chunk and
//     hid += fs_chunk @ Wo1 (split-K x24, j-tiles x4).
__global__ void k9_feat_gemv1(const float* __restrict__ query, const float* __restrict__ R,
                              const float* __restrict__ ctxE, const float* __restrict__ G,
                              const float* __restrict__ KQ, const float* __restrict__ Wo1,
                              float* __restrict__ hid) {
    int ks = blockIdx.x >> 2, jt = blockIdx.x & 3;
    int k0 = ks * 64;
    int tid = threadIdx.x;
    __shared__ float fs[64];
    __shared__ float Gs[NM * NM];
    __shared__ float aws[NM];
    __shared__ float As[NM];
    int seg = k0 >> 9;   // 0: query, 1: context_o, 2: ctxE (uniform per block)
    if (seg == 1) {
        for (int i = tid; i < NM * NM; i += 256) Gs[i] = G[i];
        __syncthreads();
        if (tid < 64) {
            int l = tid;
            float L = (l < NM) ? KQ[l] : -1e30f;
            float Aacc = 0.f;
            for (int t = 0; t < NHOPS; ++t) {
                float mxv = L;
                for (int o = 32; o > 0; o >>= 1) mxv = fmaxf(mxv, __shfl_xor(mxv, o));
                float e = (l < NM) ? __expf(L - mxv) : 0.f;
                float sm = e;
                for (int o = 32; o > 0; o >>= 1) sm += __shfl_xor(sm, o);
                float aw = e / sm;
                Aacc += aw;
                if (l < NM) aws[l] = aw;           // intra-wave LDS, hw-ordered
                if (l < NM) {
                    float d = 0.f;
                    for (int mp = 0; mp < NM; ++mp) d = fmaf(aws[mp], Gs[mp * NM + l], d);
                    L += d;
                }
            }
            if (l < NM) As[l] = Aacc;
        }
        __syncthreads();
        if (tid < 64) {
            int kk = k0 + tid - NH;                // 0..511
            float v = query[kk];
            for (int mp = 0; mp < NM; ++mp) v = fmaf(As[mp], R[mp * NH + kk], v);
            fs[tid] = fmaxf(v, 0.f);
        }
    } else if (seg == 0) {
        if (tid < 64) fs[tid] = fmaxf(query[k0 + tid], 0.f);
    } else {
        if (tid < 64) fs[tid] = fmaxf(ctxE[k0 + tid - 2 * NH], 0.f);
    }
    __syncthreads();
    int j = jt * 256 + tid;
    float acc = 0.f;
    const float4* fs4 = (const float4*)fs;
#pragma unroll
    for (int ii = 0; ii < 16; ++ii) {
        float4 f = fs4[ii];
        int k = k0 + ii * 4;
        acc = fmaf(f.x, Wo1[(size_t)k * 1024 + j], acc);
        acc = fmaf(f.y, Wo1[(size_t)(k + 1) * 1024 + j], acc);
        acc = fmaf(f.z, Wo1[(size_t)(k + 2) * 1024 + j], acc);
        acc = fmaf(f.w, Wo1[(size_t)(k + 3) * 1024 + j], acc);
    }
    atomicAdd(&hid[j], acc);
}

// ---------------------------------------------------------------------------
// K10: out += relu(hid + bo1) @ Wo2 chunk (split-K x16, v-tiles x16)
__global__ void k10_gemv2(const float* __restrict__ hid, const float* __restrict__ bo1,
                          const float* __restrict__ Wo2, float* __restrict__ out) {
    int ks = blockIdx.x >> 4, vt = blockIdx.x & 15;
    int k0 = ks * 64;
    int tid = threadIdx.x;
    __shared__ float rh[64];
    if (tid < 64) rh[tid] = fmaxf(hid[k0 + tid] + bo1[k0 + tid], 0.f);
    __syncthreads();
    int v = vt * 256 + tid;
    if (v < NV) {
        float acc = 0.f;
        const float4* rh4 = (const float4*)rh;
#pragma unroll
        for (int ii = 0; ii < 16; ++ii) {
            float4 f = rh4[ii];
            int k = k0 + ii * 4;
            acc = fmaf(f.x, Wo2[(size_t)k * NV + v], acc);
            acc = fmaf(f.y, Wo2[(size_t)(k + 1) * NV + v], acc);
            acc = fmaf(f.z, Wo2[(size_t)(k + 2) * NV + v], acc);
            acc = fmaf(f.w, Wo2[(size_t)(k + 3) * NV + v], acc);
        }
        atomicAdd(&out[v], acc);
    }
}

// ---------------------------------------------------------------------------
extern "C" void kernel_launch(void* const* d_in, const int* in_sizes, int n_in,
                              void* d_out, int out_size, void* d_ws, size_t ws_size,
                              hipStream_t stream) {
    const float* query = (const float*)d_in[0];
    const float* keys  = (const float*)d_in[1];
    const float* mvmh  = (const float*)d_in[2];
    const float* adj   = (const float*)d_in[3];
    const float* W1    = (const float*)d_in[4];
    const float* b1    = (const float*)d_in[5];
    const float* W2    = (const float*)d_in[6];
    const float* b2    = (const float*)d_in[7];
    const float* Wo1   = (const float*)d_in[8];
    const float* bo1   = (const float*)d_in[9];
    const float* Wo2   = (const float*)d_in[10];
    const float* bo2   = (const float*)d_in[11];
    float* out = (float*)d_out;

    char* w = (char*)d_ws;
    int* rcnt = (int*)w;        w += 4096 * 4;
    int* cols = (int*)w;        w += NV * CAP * 4;
    float* vals = (float*)w;    w += NV * CAP * 4;
    float* h = (float*)w;       w += (size_t)NV * NH * 4;
    float* g = (float*)w;       w += (size_t)NV * NH * 4;
    float* logits = (float*)w;  w += 4096 * 4;
    float* w2q = (float*)w;     w += NH * 4;
    float* Ppart = (float*)w;   w += (size_t)VS * NM * NH * 4;   // 640000 floats
    float* Epart = (float*)w;   w += VS * NH * 4;                // 12800 floats
    float* zreg = (float*)w;                                     // s + hid (1088 floats)
    float* s = (float*)w;       w += 64 * 4;
    float* hid = (float*)w;     w += 1024 * 4;
    float* R = (float*)w;       w += NM * NH * 4;
    float* ctxE = (float*)w;    w += NH * 4;
    float* G = (float*)w;       w += 2560 * 4;
    float* KQ = (float*)w;      w += 64 * 4;

    k1_init_csr<<<NV + 128 + 16, 256, 0, stream>>>(adj, query, W2, bo2, rcnt, cols, vals, w2q, zreg, out);
    k2_spmm_h<<<NV, 256, 0, stream>>>(rcnt, cols, vals, W1, b1, h);
    k3_spmm_g<<<NV, 256, 0, stream>>>(rcnt, cols, vals, h, w2q, g, logits);
    k5_PE<<<CB * VS, 256, 0, stream>>>(mvmh, g, logits, Ppart, Epart, s);
    k6_rowsW2<<<NM + 1, 256, 0, stream>>>(Ppart, Epart, W2, b2, s, R, ctxE);
    k7_KQG<<<NM + 1, 256, 0, stream>>>(R, query, keys, G, KQ);
    k9_feat_gemv1<<<96, 256, 0, stream>>>(query, R, ctxE, G, KQ, Wo1, hid);
    k10_gemv2<<<256, 256, 0, stream>>>(hid, bo1, Wo2, out);
}

// Round 3
// 254.217 us; speedup vs baseline: 1.0809x; 1.0312x over previous
//
#include <hip/hip_runtime.h>

// Problem constants (fixed by reference)
#define NV 4000
#define NH 512
#define NM 50
#define CAP 96
#define NHOPS 6
#define VS 25          // v-splits in kC
#define VCH 160        // NV / VS
#define CB 16          // c-chunk blocks in kC (32 cols per block, 8 per wave)

// ---------------------------------------------------------------------------
// KA: b<4000: CSR build (float4 scan) + immediately h[r] = relu(row@W1 + b1)
//     (row CSR kept in LDS; also written to global for KB).
//     b in [4000,4128): w2q = W2 @ q.  b >= 4128: out = bo2, zero s/hid.
__global__ void kA_csr_h(const float* __restrict__ adj, const float* __restrict__ query,
                         const float* __restrict__ W1, const float* __restrict__ b1,
                         const float* __restrict__ W2, const float* __restrict__ bo2,
                         int* __restrict__ rcnt, int* __restrict__ cols, float* __restrict__ vals,
                         float* __restrict__ h, float* __restrict__ w2q,
                         float* __restrict__ zreg, float* __restrict__ out) {
    int b = blockIdx.x;
    if (b < NV) {
        __shared__ int cnt;
        __shared__ int cs[CAP];
        __shared__ float vsh[CAP];
        if (threadIdx.x == 0) cnt = 0;
        __syncthreads();
        const float4* row4 = (const float4*)(adj + (size_t)b * NV);
        for (int i = threadIdx.x; i < NV / 4; i += 256) {
            float4 a = row4[i];
            if (a.x != 0.f) { int k = atomicAdd(&cnt, 1); if (k < CAP) { cs[k] = 4*i;   vsh[k] = a.x; } }
            if (a.y != 0.f) { int k = atomicAdd(&cnt, 1); if (k < CAP) { cs[k] = 4*i+1; vsh[k] = a.y; } }
            if (a.z != 0.f) { int k = atomicAdd(&cnt, 1); if (k < CAP) { cs[k] = 4*i+2; vsh[k] = a.z; } }
            if (a.w != 0.f) { int k = atomicAdd(&cnt, 1); if (k < CAP) { cs[k] = 4*i+3; vsh[k] = a.w; } }
        }
        __syncthreads();
        int n = cnt < CAP ? cnt : CAP;
        if (threadIdx.x == 0) rcnt[b] = n;
        if (threadIdx.x < n) {
            cols[b * CAP + threadIdx.x] = cs[threadIdx.x];
            vals[b * CAP + threadIdx.x] = vsh[threadIdx.x];
        }
        int c = threadIdx.x * 2;
        float2 acc = *(const float2*)(b1 + c);
        int j = 0;
        for (; j + 2 <= n; j += 2) {
            int c0 = cs[j], c1 = cs[j + 1];
            float v0 = vsh[j], v1 = vsh[j + 1];
            float2 wa = *(const float2*)(W1 + (size_t)c0 * NH + c);
            float2 wb = *(const float2*)(W1 + (size_t)c1 * NH + c);
            acc.x = fmaf(v0, wa.x, acc.x); acc.y = fmaf(v0, wa.y, acc.y);
            acc.x = fmaf(v1, wb.x, acc.x); acc.y = fmaf(v1, wb.y, acc.y);
        }
        if (j < n) {
            float2 wa = *(const float2*)(W1 + (size_t)cs[j] * NH + c);
            acc.x = fmaf(vsh[j], wa.x, acc.x); acc.y = fmaf(vsh[j], wa.y, acc.y);
        }
        float2 o = {fmaxf(acc.x, 0.f), fmaxf(acc.y, 0.f)};
        *(float2*)(h + (size_t)b * NH + c) = o;
    } else if (b < NV + 128) {
        __shared__ float qs[NH];
        qs[threadIdx.x] = query[threadIdx.x];
        qs[threadIdx.x + 256] = query[threadIdx.x + 256];
        __syncthreads();
        int wid = threadIdx.x >> 6, lane = threadIdx.x & 63;
        int k = (b - NV) * 4 + wid;
        const float* wr = W2 + (size_t)k * NH;
        float p = 0.f;
        for (int j = lane; j < NH; j += 64) p = fmaf(wr[j], qs[j], p);
        for (int o = 32; o > 0; o >>= 1) p += __shfl_down(p, o);
        if (lane == 0) w2q[k] = p;
    } else {
        int t = (b - NV - 128) * 256 + threadIdx.x;   // 0..4095
        if (t < NV) out[t] = bo2[t];
        if (t < 1088) zreg[t] = 0.f;                  // s[64] + hid[1024]
    }
}

// ---------------------------------------------------------------------------
// KB: g = spmm(adj, h); fused logits[r] = dot(g[r,:], w2q)  (unroll-2 gather)
__global__ void kB_spmm_g(const int* __restrict__ rcnt, const int* __restrict__ cols,
                          const float* __restrict__ vals, const float* __restrict__ h,
                          const float* __restrict__ w2q, float* __restrict__ g,
                          float* __restrict__ logits) {
    int r = blockIdx.x;
    __shared__ int cs[CAP];
    __shared__ float vsh[CAP];
    __shared__ float red[4];
    int cnt = rcnt[r];
    if (threadIdx.x < cnt) {
        cs[threadIdx.x] = cols[r * CAP + threadIdx.x] * NH;
        vsh[threadIdx.x] = vals[r * CAP + threadIdx.x];
    }
    __syncthreads();
    int c = threadIdx.x * 2;
    float2 acc = {0.f, 0.f};
    int j = 0;
    for (; j + 2 <= cnt; j += 2) {
        int c0 = cs[j], c1 = cs[j + 1];
        float v0 = vsh[j], v1 = vsh[j + 1];
        float2 wa = *(const float2*)(h + (size_t)c0 + c);
        float2 wb = *(const float2*)(h + (size_t)c1 + c);
        acc.x = fmaf(v0, wa.x, acc.x); acc.y = fmaf(v0, wa.y, acc.y);
        acc.x = fmaf(v1, wb.x, acc.x); acc.y = fmaf(v1, wb.y, acc.y);
    }
    if (j < cnt) {
        float2 wa = *(const float2*)(h + (size_t)cs[j] + c);
        acc.x = fmaf(vsh[j], wa.x, acc.x); acc.y = fmaf(vsh[j], wa.y, acc.y);
    }
    *(float2*)(g + (size_t)r * NH + c) = acc;
    float2 wq = *(const float2*)(w2q + c);
    float pp = acc.x * wq.x + acc.y * wq.y;
    for (int o = 32; o > 0; o >>= 1) pp += __shfl_down(pp, o);
    if ((threadIdx.x & 63) == 0) red[threadIdx.x >> 6] = pp;
    __syncthreads();
    if (threadIdx.x == 0) logits[r] = red[0] + red[1] + red[2] + red[3];
}

// ---------------------------------------------------------------------------
// KC: Ppart[vs] = mvmh_chunk @ g_chunk, Epart[vs] = aw_e_chunk @ g_chunk,
//     s = rowsum(mvmh). lane = m; g fetched as wave-uniform broadcast float4;
//     mvmh chunk staged in LDS (stride 161 -> conflict-free across lanes).
//     Softmax scalars (mx, inv) computed redundantly per block.
__global__ void kC_PE(const float* __restrict__ mvmh, const float* __restrict__ g,
                      const float* __restrict__ logits, float* __restrict__ Ppart,
                      float* __restrict__ Epart, float* __restrict__ s) {
    __shared__ float mvs[NM * (VCH + 1)];
    __shared__ float es[VCH];
    __shared__ float red[4];
    int cb = blockIdx.x & (CB - 1);
    int vs = blockIdx.x / CB;
    int v0 = vs * VCH;
    int tid = threadIdx.x;

    for (int i = tid; i < NM * VCH; i += 256) {
        int m = i / VCH, vv = i - m * VCH;
        mvs[m * (VCH + 1) + vv] = mvmh[(size_t)m * NV + v0 + vv];
    }
    float lmx = -1e30f;
    for (int i = tid; i < NV; i += 256) lmx = fmaxf(lmx, logits[i]);
    for (int o = 32; o > 0; o >>= 1) lmx = fmaxf(lmx, __shfl_xor(lmx, o));
    if ((tid & 63) == 0) red[tid >> 6] = lmx;
    __syncthreads();
    float mx = fmaxf(fmaxf(red[0], red[1]), fmaxf(red[2], red[3]));
    __syncthreads();
    float lsum = 0.f;
    for (int i = tid; i < NV; i += 256) lsum += __expf(logits[i] - mx);
    for (int o = 32; o > 0; o >>= 1) lsum += __shfl_xor(lsum, o);
    if ((tid & 63) == 0) red[tid >> 6] = lsum;
    __syncthreads();
    float inv = 1.f / (red[0] + red[1] + red[2] + red[3]);
    for (int i = tid; i < VCH; i += 256) es[i] = __expf(logits[v0 + i] - mx) * inv;
    __syncthreads();

    int w = tid >> 6, l = tid & 63;
    int C = cb * 32 + w * 8;
    int lc = (l < NM) ? l : 0;
    const float* mrow = mvs + lc * (VCH + 1);
    float acc[8], ace[8];
    float accs = 0.f;
#pragma unroll
    for (int i = 0; i < 8; ++i) { acc[i] = 0.f; ace[i] = 0.f; }
    for (int vv = 0; vv < VCH; ++vv) {
        int v = v0 + vv;
        float t = mrow[vv];
        float ve = es[vv];
        float4 ga = *(const float4*)(g + (size_t)v * NH + C);
        float4 gb = *(const float4*)(g + (size_t)v * NH + C + 4);
        acc[0] = fmaf(t, ga.x, acc[0]); ace[0] = fmaf(ve, ga.x, ace[0]);
        acc[1] = fmaf(t, ga.y, acc[1]); ace[1] = fmaf(ve, ga.y, ace[1]);
        acc[2] = fmaf(t, ga.z, acc[2]); ace[2] = fmaf(ve, ga.z, ace[2]);
        acc[3] = fmaf(t, ga.w, acc[3]); ace[3] = fmaf(ve, ga.w, ace[3]);
        acc[4] = fmaf(t, gb.x, acc[4]); ace[4] = fmaf(ve, gb.x, ace[4]);
        acc[5] = fmaf(t, gb.y, acc[5]); ace[5] = fmaf(ve, gb.y, ace[5]);
        acc[6] = fmaf(t, gb.z, acc[6]); ace[6] = fmaf(ve, gb.z, ace[6]);
        acc[7] = fmaf(t, gb.w, acc[7]); ace[7] = fmaf(ve, gb.w, ace[7]);
        accs += t;
    }
    if (l < NM) {
        float* dst = Ppart + ((size_t)vs * NM + l) * NH + C;
        float4 o0 = {acc[0], acc[1], acc[2], acc[3]};
        float4 o1 = {acc[4], acc[5], acc[6], acc[7]};
        *(float4*)dst = o0;
        *(float4*)(dst + 4) = o1;
    }
    if (l == 0) {
        float* dst = Epart + (size_t)vs * NH + C;
        float4 e0 = {ace[0], ace[1], ace[2], ace[3]};
        float4 e1 = {ace[4], ace[5], ace[6], ace[7]};
        *(float4*)dst = e0;
        *(float4*)(dst + 4) = e1;
    }
    if (cb == 0 && w == 0 && l < NM) atomicAdd(&s[l], accs);
}

// ---------------------------------------------------------------------------
// KD: reduce partials -> xs; R[m] = xs@W2 + s[m]*b2 (m<50) / ctxE = xs@W2 + b2
//     (m==50); then in the same block G[m,mm] = dot(R[m], keys[mm]) (or
//     KQ[mm] = dot(query, keys[mm]) for m==50).
__global__ void kD_rowsW2_KQG(const float* __restrict__ Ppart, const float* __restrict__ Epart,
                              const float* __restrict__ W2, const float* __restrict__ b2,
                              const float* __restrict__ s, const float* __restrict__ query,
                              const float* __restrict__ keys, float* __restrict__ R,
                              float* __restrict__ ctxE, float* __restrict__ G,
                              float* __restrict__ KQ) {
    int m = blockIdx.x;
    __shared__ float xs[NH];
    __shared__ float ys[NH];
    int tid = threadIdx.x;   // 256
    if (m < NM) {
        for (int k = tid; k < NH; k += 256) {
            float v = 0.f;
            const float* p = Ppart + (size_t)m * NH + k;
            for (int q = 0; q < VS; ++q) v += p[(size_t)q * NM * NH];
            xs[k] = v;
        }
    } else {
        for (int k = tid; k < NH; k += 256) {
            float v = 0.f;
            for (int q = 0; q < VS; ++q) v += Epart[(size_t)q * NH + k];
            xs[k] = v;
        }
    }
    __syncthreads();
    int c = tid * 2;
    float2 acc = {0.f, 0.f};
    const float4* xs4 = (const float4*)xs;
    for (int kk = 0; kk < NH / 4; ++kk) {
        float4 x = xs4[kk];
        int k = kk * 4;
        float2 w0 = *(const float2*)(W2 + (size_t)k * NH + c);
        float2 w1 = *(const float2*)(W2 + (size_t)(k + 1) * NH + c);
        float2 w2v = *(const float2*)(W2 + (size_t)(k + 2) * NH + c);
        float2 w3 = *(const float2*)(W2 + (size_t)(k + 3) * NH + c);
        acc.x = fmaf(x.x, w0.x, acc.x);  acc.y = fmaf(x.x, w0.y, acc.y);
        acc.x = fmaf(x.y, w1.x, acc.x);  acc.y = fmaf(x.y, w1.y, acc.y);
        acc.x = fmaf(x.z, w2v.x, acc.x); acc.y = fmaf(x.z, w2v.y, acc.y);
        acc.x = fmaf(x.w, w3.x, acc.x);  acc.y = fmaf(x.w, w3.y, acc.y);
    }
    float2 bb = *(const float2*)(b2 + c);
    if (m < NM) {
        float sm = s[m];
        acc.x += sm * bb.x;
        acc.y += sm * bb.y;
        *(float2*)(R + (size_t)m * NH + c) = acc;
        ys[c] = acc.x; ys[c + 1] = acc.y;
    } else {
        acc.x += bb.x;
        acc.y += bb.y;
        *(float2*)(ctxE + c) = acc;
        float2 q2 = *(const float2*)(query + c);
        ys[c] = q2.x; ys[c + 1] = q2.y;
    }
    __syncthreads();
    int wid = tid >> 6, lane = tid & 63;
    for (int mm = wid; mm < NM; mm += 4) {
        const float* kr = keys + (size_t)mm * NH;
        float p = 0.f;
        for (int jj = lane; jj < NH; jj += 64) p = fmaf(kr[jj], ys[jj], p);
        for (int o = 32; o > 0; o >>= 1) p += __shfl_down(p, o);
        if (lane == 0) {
            if (m < NM) G[m * NM + mm] = p;
            else KQ[mm] = p;
        }
    }
}

// ---------------------------------------------------------------------------
// KE: blocks needing feat[512..1024) run the 6-hop 50-dim recurrence
//     redundantly (wave 0), then all blocks compute their fs chunk and
//     hid += fs_chunk @ Wo1 (split-K x24, j-tiles x4).
__global__ void kE_feat_gemv1(const float* __restrict__ query, const float* __restrict__ R,
                              const float* __restrict__ ctxE, const float* __restrict__ G,
                              const float* __restrict__ KQ, const float* __restrict__ Wo1,
                              float* __restrict__ hid) {
    int ks = blockIdx.x >> 2, jt = blockIdx.x & 3;
    int k0 = ks * 64;
    int tid = threadIdx.x;
    __shared__ float fs[64];
    __shared__ float Gs[NM * NM];
    __shared__ float aws[NM];
    __shared__ float As[NM];
    int seg = k0 >> 9;   // 0: query, 1: context_o, 2: ctxE (uniform per block)
    if (seg == 1) {
        for (int i = tid; i < NM * NM; i += 256) Gs[i] = G[i];
        __syncthreads();
        if (tid < 64) {
            int l = tid;
            float L = (l < NM) ? KQ[l] : -1e30f;
            float Aacc = 0.f;
            for (int t = 0; t < NHOPS; ++t) {
                float mxv = L;
                for (int o = 32; o > 0; o >>= 1) mxv = fmaxf(mxv, __shfl_xor(mxv, o));
                float e = (l < NM) ? __expf(L - mxv) : 0.f;
                float sm = e;
                for (int o = 32; o > 0; o >>= 1) sm += __shfl_xor(sm, o);
                float aw = e / sm;
                Aacc += aw;
                if (l < NM) aws[l] = aw;           // intra-wave LDS, hw-ordered
                if (l < NM) {
                    float d = 0.f;
                    for (int mp = 0; mp < NM; ++mp) d = fmaf(aws[mp], Gs[mp * NM + l], d);
                    L += d;
                }
            }
            if (l < NM) As[l] = Aacc;
        }
        __syncthreads();
        if (tid < 64) {
            int kk = k0 + tid - NH;                // 0..511
            float v = query[kk];
            for (int mp = 0; mp < NM; ++mp) v = fmaf(As[mp], R[mp * NH + kk], v);
            fs[tid] = fmaxf(v, 0.f);
        }
    } else if (seg == 0) {
        if (tid < 64) fs[tid] = fmaxf(query[k0 + tid], 0.f);
    } else {
        if (tid < 64) fs[tid] = fmaxf(ctxE[k0 + tid - 2 * NH], 0.f);
    }
    __syncthreads();
    int j = jt * 256 + tid;
    float acc = 0.f;
    const float4* fs4 = (const float4*)fs;
#pragma unroll
    for (int ii = 0; ii < 16; ++ii) {
        float4 f = fs4[ii];
        int k = k0 + ii * 4;
        acc = fmaf(f.x, Wo1[(size_t)k * 1024 + j], acc);
        acc = fmaf(f.y, Wo1[(size_t)(k + 1) * 1024 + j], acc);
        acc = fmaf(f.z, Wo1[(size_t)(k + 2) * 1024 + j], acc);
        acc = fmaf(f.w, Wo1[(size_t)(k + 3) * 1024 + j], acc);
    }
    atomicAdd(&hid[j], acc);
}

// ---------------------------------------------------------------------------
// KF: out += relu(hid + bo1) @ Wo2 chunk (split-K x16, v-tiles x16)
__global__ void kF_gemv2(const float* __restrict__ hid, const float* __restrict__ bo1,
                         const float* __restrict__ Wo2, float* __restrict__ out) {
    int ks = blockIdx.x >> 4, vt = blockIdx.x & 15;
    int k0 = ks * 64;
    int tid = threadIdx.x;
    __shared__ float rh[64];
    if (tid < 64) rh[tid] = fmaxf(hid[k0 + tid] + bo1[k0 + tid], 0.f);
    __syncthreads();
    int v = vt * 256 + tid;
    if (v < NV) {
        float acc = 0.f;
        const float4* rh4 = (const float4*)rh;
#pragma unroll
        for (int ii = 0; ii < 16; ++ii) {
            float4 f = rh4[ii];
            int k = k0 + ii * 4;
            acc = fmaf(f.x, Wo2[(size_t)k * NV + v], acc);
            acc = fmaf(f.y, Wo2[(size_t)(k + 1) * NV + v], acc);
            acc = fmaf(f.z, Wo2[(size_t)(k + 2) * NV + v], acc);
            acc = fmaf(f.w, Wo2[(size_t)(k + 3) * NV + v], acc);
        }
        atomicAdd(&out[v], acc);
    }
}

// ---------------------------------------------------------------------------
extern "C" void kernel_launch(void* const* d_in, const int* in_sizes, int n_in,
                              void* d_out, int out_size, void* d_ws, size_t ws_size,
                              hipStream_t stream) {
    const float* query = (const float*)d_in[0];
    const float* keys  = (const float*)d_in[1];
    const float* mvmh  = (const float*)d_in[2];
    const float* adj   = (const float*)d_in[3];
    const float* W1    = (const float*)d_in[4];
    const float* b1    = (const float*)d_in[5];
    const float* W2    = (const float*)d_in[6];
    const float* b2    = (const float*)d_in[7];
    const float* Wo1   = (const float*)d_in[8];
    const float* bo1   = (const float*)d_in[9];
    const float* Wo2   = (const float*)d_in[10];
    const float* bo2   = (const float*)d_in[11];
    float* out = (float*)d_out;

    char* w = (char*)d_ws;
    int* rcnt = (int*)w;        w += 4096 * 4;
    int* cols = (int*)w;        w += NV * CAP * 4;
    float* vals = (float*)w;    w += NV * CAP * 4;
    float* h = (float*)w;       w += (size_t)NV * NH * 4;
    float* g = (float*)w;       w += (size_t)NV * NH * 4;
    float* logits = (float*)w;  w += 4096 * 4;
    float* w2q = (float*)w;     w += NH * 4;
    float* Ppart = (float*)w;   w += (size_t)VS * NM * NH * 4;   // 640000 floats
    float* Epart = (float*)w;   w += VS * NH * 4;                // 12800 floats
    float* zreg = (float*)w;                                     // s + hid (1088 floats)
    float* s = (float*)w;       w += 64 * 4;
    float* hid = (float*)w;     w += 1024 * 4;
    float* R = (float*)w;       w += NM * NH * 4;
    float* ctxE = (float*)w;    w += NH * 4;
    float* G = (float*)w;       w += 2560 * 4;
    float* KQ = (float*)w;      w += 64 * 4;

    kA_csr_h<<<NV + 128 + 16, 256, 0, stream>>>(adj, query, W1, b1, W2, bo2,
                                                rcnt, cols, vals, h, w2q, zreg, out);
    kB_spmm_g<<<NV, 256, 0, stream>>>(rcnt, cols, vals, h, w2q, g, logits);
    kC_PE<<<CB * VS, 256, 0, stream>>>(mvmh, g, logits, Ppart, Epart, s);
    kD_rowsW2_KQG<<<NM + 1, 256, 0, stream>>>(Ppart, Epart, W2, b2, s, query, keys,
                                              R, ctxE, G, KQ);
    kE_feat_gemv1<<<96, 256, 0, stream>>>(query, R, ctxE, G, KQ, Wo1, hid);
    kF_gemv2<<<256, 256, 0, stream>>>(hid, bo1, Wo2, out);
}